// Round 3
// baseline (816.044 us; speedup 1.0000x reference)
//
#include <hip/hip_runtime.h>
#include <stdint.h>

#define N_PROP 100000
#define N_CLS  91
#define NFG    90          // foreground classes
#define TOPK   1000
#define NWORD  16          // 1000 bits -> 16 u64 words
#define CAND_MAX 2048
#define DETS   100
#define CHUNK  12500       // N_PROP / 8
#define SCORE_THRESH 0.05f
#define BBOX_CLIP 4.135166556742356f   // log(1000/16)

__device__ __forceinline__ float clampf(float v, float lo, float hi) {
    return fminf(fmaxf(v, lo), hi);
}

// ---------------------------------------------------------------------------
// Kernel 0: zero the global histogram / counter scratch
// ---------------------------------------------------------------------------
__global__ __launch_bounds__(256) void zero_kernel(
    unsigned int* __restrict__ p, int n) {
    for (int i = blockIdx.x * 256 + threadIdx.x; i < n; i += gridDim.x * 256)
        p[i] = 0u;
}

// ---------------------------------------------------------------------------
// Kernel 1: softmax over 91 classes, write transposed scores_t[90][N_PROP]
// ---------------------------------------------------------------------------
__global__ __launch_bounds__(256) void softmax_kernel(
    const float* __restrict__ logits, float* __restrict__ scores_t) {
    int row = blockIdx.x * blockDim.x + threadIdx.x;
    if (row >= N_PROP) return;
    const float* lrow = logits + (size_t)row * N_CLS;
    float m = -INFINITY;
    for (int c = 0; c < N_CLS; ++c) m = fmaxf(m, lrow[c]);
    float sum = 0.f;
    for (int c = 0; c < N_CLS; ++c) sum += expf(lrow[c] - m);
    for (int c = 1; c < N_CLS; ++c) {
        float s = expf(lrow[c] - m) / sum;
        scores_t[(size_t)(c - 1) * N_PROP + row] = s;  // coalesced per-c
    }
}

// ---------------------------------------------------------------------------
// Selection, restructured for occupancy (was: 90 blocks doing 3 passes over
// 36 MB from 90 CUs; now each pass is 720 blocks):
//   hist1: per-class level-1 histogram (bits>>20) into ghist1[c][1024]
//   hist2: per-class level-2 histogram of bin b1 (bits>>10 & 1023)
//   compact: elements with (bits>>10) >= thresh22 -> gcand[c] (atomic cnt)
//   sortout: bitonic sort 2048 keys -> sel_score/sel_idx (bit-identical order)
// ---------------------------------------------------------------------------
__device__ __forceinline__ void suffix_scan_1024(unsigned int* sh, int tid) {
    for (int off = 1; off < 1024; off <<= 1) {
        unsigned int v[4];
#pragma unroll
        for (int q = 0; q < 4; ++q) {
            int x = tid + q * 256;
            v[q] = (x + off < 1024) ? sh[x + off] : 0u;
        }
        __syncthreads();
#pragma unroll
        for (int q = 0; q < 4; ++q) sh[tid + q * 256] += v[q];
        __syncthreads();
    }
}

__global__ __launch_bounds__(256) void hist1_kernel(
    const float* __restrict__ scores_t, unsigned int* __restrict__ ghist1) {
    const int c = blockIdx.x, chunk = blockIdx.y, tid = threadIdx.x;
    __shared__ unsigned int lh[4][1024];
    for (int i = tid; i < 4096; i += 256) (&lh[0][0])[i] = 0u;
    __syncthreads();
    const float* sc = scores_t + (size_t)c * N_PROP + chunk * CHUNK;
    for (int i = tid; i < CHUNK; i += 256) {
        unsigned int bits = __float_as_uint(sc[i]);
        atomicAdd(&lh[tid & 3][bits >> 20], 1u);
    }
    __syncthreads();
    for (int b = tid; b < 1024; b += 256) {
        unsigned int v = lh[0][b] + lh[1][b] + lh[2][b] + lh[3][b];
        if (v) atomicAdd(&ghist1[c * 1024 + b], v);
    }
}

__global__ __launch_bounds__(256) void hist2_kernel(
    const float* __restrict__ scores_t, const unsigned int* __restrict__ ghist1,
    unsigned int* __restrict__ ghist2) {
    const int c = blockIdx.x, chunk = blockIdx.y, tid = threadIdx.x;
    __shared__ unsigned int sh[1024];
    __shared__ unsigned int s_b1;
#pragma unroll
    for (int q = 0; q < 4; ++q) sh[tid + q * 256] = ghist1[c * 1024 + tid + q * 256];
    __syncthreads();
    suffix_scan_1024(sh, tid);
#pragma unroll
    for (int q = 0; q < 4; ++q) {
        int x = tid + q * 256;
        if (sh[x] >= TOPK && (x == 1023 || sh[x + 1] < TOPK)) s_b1 = (unsigned)x;
    }
    __syncthreads();
    const unsigned int b1 = s_b1;
    __syncthreads();
#pragma unroll
    for (int q = 0; q < 4; ++q) sh[tid + q * 256] = 0u;   // reuse as local hist2
    __syncthreads();
    const float* sc = scores_t + (size_t)c * N_PROP + chunk * CHUNK;
    for (int i = tid; i < CHUNK; i += 256) {
        unsigned int bits = __float_as_uint(sc[i]);
        if ((bits >> 20) == b1) atomicAdd(&sh[(bits >> 10) & 1023u], 1u);
    }
    __syncthreads();
    for (int b = tid; b < 1024; b += 256)
        if (sh[b]) atomicAdd(&ghist2[c * 1024 + b], sh[b]);
}

__global__ __launch_bounds__(256) void compact_kernel(
    const float* __restrict__ scores_t, const unsigned int* __restrict__ ghist1,
    const unsigned int* __restrict__ ghist2, unsigned int* __restrict__ gcnt,
    unsigned long long* __restrict__ gcand) {
    const int c = blockIdx.x, chunk = blockIdx.y, tid = threadIdx.x;
    __shared__ unsigned int sh[1024];
    __shared__ unsigned int s_b1, s_above, s_b2;
#pragma unroll
    for (int q = 0; q < 4; ++q) sh[tid + q * 256] = ghist1[c * 1024 + tid + q * 256];
    __syncthreads();
    suffix_scan_1024(sh, tid);
#pragma unroll
    for (int q = 0; q < 4; ++q) {
        int x = tid + q * 256;
        if (sh[x] >= TOPK && (x == 1023 || sh[x + 1] < TOPK)) {
            s_b1 = (unsigned)x;
            s_above = (x == 1023) ? 0u : sh[x + 1];
        }
    }
    __syncthreads();
    const unsigned int b1 = s_b1;
    const unsigned int need2 = TOPK - s_above;
    __syncthreads();
#pragma unroll
    for (int q = 0; q < 4; ++q) sh[tid + q * 256] = ghist2[c * 1024 + tid + q * 256];
    __syncthreads();
    suffix_scan_1024(sh, tid);
#pragma unroll
    for (int q = 0; q < 4; ++q) {
        int x = tid + q * 256;
        if (sh[x] >= need2 && (x == 1023 || sh[x + 1] < need2)) s_b2 = (unsigned)x;
    }
    __syncthreads();
    const unsigned int thresh22 = (b1 << 10) | s_b2;
    const float* sc = scores_t + (size_t)c * N_PROP + chunk * CHUNK;
    const int ibase = chunk * CHUNK;
    for (int i = tid; i < CHUNK; i += 256) {
        unsigned int bits = __float_as_uint(sc[i]);
        if ((bits >> 10) >= thresh22) {
            unsigned int pos = atomicAdd(&gcnt[c], 1u);
            if (pos < CAND_MAX)
                gcand[(size_t)c * CAND_MAX + pos] =
                    ((unsigned long long)bits << 32) |
                    (unsigned int)(~(unsigned int)(ibase + i));
        }
    }
}

__global__ __launch_bounds__(1024) void sortout_kernel(
    const unsigned long long* __restrict__ gcand,
    const unsigned int* __restrict__ gcnt,
    float* __restrict__ sel_score, int* __restrict__ sel_idx) {
    const int c = blockIdx.x, tid = threadIdx.x;
    __shared__ unsigned long long cand[CAND_MAX];
    unsigned int cnt = gcnt[c];
    if (cnt > CAND_MAX) cnt = CAND_MAX;
    for (int i = tid; i < CAND_MAX; i += 1024)
        cand[i] = ((unsigned)i < cnt) ? gcand[(size_t)c * CAND_MAX + i] : 0ull;
    __syncthreads();
    for (unsigned int k = 2; k <= CAND_MAX; k <<= 1) {
        for (unsigned int j = k >> 1; j > 0; j >>= 1) {
            for (unsigned int i = tid; i < CAND_MAX; i += 1024) {
                unsigned int ixj = i ^ j;
                if (ixj > i) {
                    unsigned long long a = cand[i], b = cand[ixj];
                    bool desc = ((i & k) == 0);
                    if (desc ? (a < b) : (a > b)) { cand[i] = b; cand[ixj] = a; }
                }
            }
            __syncthreads();
        }
    }
    if (tid < TOPK) {
        unsigned long long kk = cand[tid];
        sel_score[c * TOPK + tid] = __uint_as_float((unsigned int)(kk >> 32));
        sel_idx[c * TOPK + tid] = (int)(~(unsigned int)(kk & 0xFFFFFFFFull));
    }
}

// ---------------------------------------------------------------------------
// Kernel 3: decode + clip the 90k selected boxes only
// ---------------------------------------------------------------------------
__global__ __launch_bounds__(256) void decode_kernel(
    const float* __restrict__ box_reg, const float* __restrict__ proposals,
    const int* __restrict__ sel_idx, float* __restrict__ sel_box) {
#pragma clang fp contract(off)
    int t = blockIdx.x * blockDim.x + threadIdx.x;
    if (t >= NFG * TOPK) return;
    int c = t / TOPK;           // fg class index, label = c+1
    int i = sel_idx[t];
    float x1 = proposals[i * 4 + 0], y1 = proposals[i * 4 + 1];
    float x2 = proposals[i * 4 + 2], y2 = proposals[i * 4 + 3];
    float w = x2 - x1 + 1.0f, h = y2 - y1 + 1.0f;
    float cx = x1 + 0.5f * w, cy = y1 + 0.5f * h;
    const float* d = box_reg + (size_t)i * (N_CLS * 4) + (size_t)(c + 1) * 4;
    float dx = d[0] / 10.0f, dy = d[1] / 10.0f;
    float dw = fminf(d[2] / 5.0f, BBOX_CLIP);
    float dh = fminf(d[3] / 5.0f, BBOX_CLIP);
    float pcx = dx * w + cx, pcy = dy * h + cy;
    float pw = expf(dw) * w, ph = expf(dh) * h;
    float ox1 = clampf(pcx - 0.5f * pw, 0.f, 1332.f);
    float oy1 = clampf(pcy - 0.5f * ph, 0.f, 799.f);
    float ox2 = clampf(pcx + 0.5f * pw - 1.0f, 0.f, 1332.f);
    float oy2 = clampf(pcy + 0.5f * ph - 1.0f, 0.f, 799.f);
    float4 o = make_float4(ox1, oy1, ox2, oy2);
    ((float4*)sel_box)[t] = o;
}

// ---------------------------------------------------------------------------
// Kernel 4a: suppression bitmask. R2: grid (class, 4 row-chunks, 4 j-tiles)
// = 1440 blocks (R1 was 360 -> 8.5% occupancy, latency-bound). Broadcast LDS
// reads kept (0 conflicts); area[j] recomputed in VALU (5 flops) instead of a
// second ds_read to halve LDS-pipe pressure. Below-diagonal tiles exit early.
// ---------------------------------------------------------------------------
__global__ __launch_bounds__(256) void mask_kernel(
    const float* __restrict__ sel_box, unsigned long long* __restrict__ mask) {
#pragma clang fp contract(off)
    const int c = blockIdx.x;
    const int rbase = blockIdx.y * 256;
    const int jbase0 = blockIdx.z * 256;   // tile of 4 words
    const int r = rbase + threadIdx.x;
    unsigned long long* mrow = mask + ((size_t)c * TOPK + r) * NWORD;
    if (jbase0 + 255 <= rbase) {           // whole tile below diagonal
        if (r < TOPK) {
#pragma unroll
            for (int w4 = 0; w4 < 4; ++w4) mrow[blockIdx.z * 4 + w4] = 0ull;
        }
        return;
    }
    __shared__ float4 box[256];
    {
        int jload = jbase0 + threadIdx.x;
        if (jload < TOPK)
            box[threadIdx.x] = ((const float4*)sel_box)[c * TOPK + jload];
    }
    __syncthreads();
    if (r >= TOPK) return;
    const float4 br = ((const float4*)sel_box)[c * TOPK + r];
    const float ar = (br.z - br.x + 1.0f) * (br.w - br.y + 1.0f);
    for (int w4 = 0; w4 < 4; ++w4) {
        const int wglob = blockIdx.z * 4 + w4;
        const int jbase = wglob * 64;
        if (jbase + 63 <= r) { mrow[wglob] = 0ull; continue; }
        unsigned long long bits = 0ull;
        const int jend = (jbase + 64 < TOPK) ? jbase + 64 : TOPK;
        for (int j = jbase; j < jend; ++j) {
            float4 bj = box[j - jbase0];         // broadcast (uniform addr)
            float aj = (bj.z - bj.x + 1.0f) * (bj.w - bj.y + 1.0f);
            float ltx = fmaxf(br.x, bj.x), lty = fmaxf(br.y, bj.y);
            float rbx = fminf(br.z, bj.z), rby = fminf(br.w, bj.w);
            float iw = fmaxf(rbx - ltx + 1.0f, 0.f);
            float ih = fmaxf(rby - lty + 1.0f, 0.f);
            float inter = iw * ih;
            float uni = ar + aj - inter;
            float diff = (inter + inter) - uni;  // sign always exact
            bool sup;
            if (uni > 0.f && fabsf(diff) > uni * 5e-7f) {
                sup = diff > 0.f;                // fast path (taken ~always)
            } else {
                sup = (inter / uni) > 0.5f;      // exact-window fallback
            }
            if (sup && j > r) bits |= 1ull << (j - jbase);
        }
        mrow[wglob] = bits;
    }
}

// ---------------------------------------------------------------------------
// Kernel 4b: serial greedy sweep over the bitmask, one wave per class.
// ---------------------------------------------------------------------------
__global__ __launch_bounds__(64) void nms_reduce_kernel(
    const unsigned long long* __restrict__ mask, float* __restrict__ sel_score) {
    const int c = blockIdx.x;
    const int lane = threadIdx.x;
    __shared__ unsigned long long keep_lds[NWORD];

    unsigned long long keep = 0ull;
    for (int w = 0; w < NWORD; ++w) {
        int j = w * 64 + lane;
        float s = (j < TOPK) ? sel_score[c * TOPK + j] : -1.0f;
        unsigned long long m = __ballot(s > SCORE_THRESH);
        if (lane == w) keep = m;
    }

    const unsigned long long* mrow = mask + (size_t)c * TOPK * NWORD;
    const int w = (lane < NWORD) ? lane : 0;
    unsigned long long pre[8];
#pragma unroll
    for (int d = 0; d < 8; ++d) pre[d] = mrow[(size_t)d * NWORD + w];

    for (int i = 0; i < TOPK; i += 8) {
#pragma unroll
        for (int d = 0; d < 8; ++d) {
            int ii = i + d;
            unsigned long long row = pre[d];
            pre[d] = (ii + 8 < TOPK) ? mrow[(size_t)(ii + 8) * NWORD + w] : 0ull;
            unsigned long long kw = __shfl(keep, ii >> 6);
            if ((kw >> (ii & 63)) & 1ull) keep &= ~row;
        }
    }
    if (lane < NWORD) keep_lds[lane] = keep;
    __syncthreads();
    for (int j = lane; j < TOPK; j += 64) {
        bool k = (keep_lds[j >> 6] >> (j & 63)) & 1ull;
        if (!k) sel_score[c * TOPK + j] = -1.0f;
    }
}

// ---------------------------------------------------------------------------
// Kernel 5: global top-100 of the 90000 candidate scores (stable desc)
// ---------------------------------------------------------------------------
__global__ __launch_bounds__(1024) void final_topk_kernel(
    const float* __restrict__ sel_score, const float* __restrict__ sel_box,
    float* __restrict__ out) {
    const int tid = threadIdx.x;
    const int M = NFG * TOPK;
    __shared__ unsigned int hist[8][1024];
    __shared__ unsigned long long cand[CAND_MAX];
    __shared__ unsigned int s_cnt, s_b1, s_above, s_b2;

    unsigned int local = 0;
    for (int i = tid; i < M; i += 1024) local += (sel_score[i] > SCORE_THRESH);
    hist[0][tid] = local;
    __syncthreads();
    for (int off = 512; off > 0; off >>= 1) {
        if (tid < off) hist[0][tid] += hist[0][tid + off];
        __syncthreads();
    }
    const bool usefilter = hist[0][0] >= DETS;
    __syncthreads();
    for (int i = tid; i < 8 * 1024; i += 1024) (&hist[0][0])[i] = 0u;
    if (tid == 0) s_cnt = 0u;
    __syncthreads();

    for (int i = tid; i < M; i += 1024) {
        float s = sel_score[i];
        if (usefilter && !(s > SCORE_THRESH)) continue;
        unsigned int u = __float_as_uint(s);
        unsigned int o = (u & 0x80000000u) ? ~u : (u | 0x80000000u);
        atomicAdd(&hist[tid & 7][o >> 22], 1u);
    }
    __syncthreads();
    unsigned int merged = 0;
    for (int r = 0; r < 8; ++r) merged += hist[r][tid];
    __syncthreads();
    hist[0][tid] = merged;
    __syncthreads();
    for (int off = 1; off < 1024; off <<= 1) {
        unsigned int v = (tid + off < 1024) ? hist[0][tid + off] : 0u;
        __syncthreads();
        hist[0][tid] += v;
        __syncthreads();
    }
    if (hist[0][tid] >= DETS && (tid == 1023 || hist[0][tid + 1] < DETS)) {
        s_b1 = (unsigned)tid;
        s_above = (tid == 1023) ? 0u : hist[0][tid + 1];
    }
    __syncthreads();
    const unsigned int b1 = s_b1, above = s_above;
    const unsigned int need2 = DETS - above;
    __syncthreads();
    hist[0][tid] = 0u;
    __syncthreads();
    for (int i = tid; i < M; i += 1024) {
        float s = sel_score[i];
        if (usefilter && !(s > SCORE_THRESH)) continue;
        unsigned int u = __float_as_uint(s);
        unsigned int o = (u & 0x80000000u) ? ~u : (u | 0x80000000u);
        if ((o >> 22) == b1) atomicAdd(&hist[0][(o >> 12) & 1023u], 1u);
    }
    __syncthreads();
    for (int off = 1; off < 1024; off <<= 1) {
        unsigned int v = (tid + off < 1024) ? hist[0][tid + off] : 0u;
        __syncthreads();
        hist[0][tid] += v;
        __syncthreads();
    }
    if (hist[0][tid] >= need2 && (tid == 1023 || hist[0][tid + 1] < need2))
        s_b2 = (unsigned)tid;
    __syncthreads();
    const unsigned int thresh20 = (b1 << 10) | s_b2;
    for (int i = tid; i < M; i += 1024) {
        float s = sel_score[i];
        if (usefilter && !(s > SCORE_THRESH)) continue;
        unsigned int u = __float_as_uint(s);
        unsigned int o = (u & 0x80000000u) ? ~u : (u | 0x80000000u);
        if ((o >> 12) >= thresh20) {
            unsigned int pos = atomicAdd(&s_cnt, 1u);
            if (pos < CAND_MAX)
                cand[pos] = ((unsigned long long)o << 32) |
                            (unsigned int)(~(unsigned int)i);
        }
    }
    __syncthreads();
    unsigned int cnt = s_cnt < CAND_MAX ? s_cnt : CAND_MAX;
    for (int i = tid; i < CAND_MAX; i += 1024)
        if ((unsigned)i >= cnt) cand[i] = 0ull;
    __syncthreads();
    for (unsigned int k = 2; k <= CAND_MAX; k <<= 1) {
        for (unsigned int j = k >> 1; j > 0; j >>= 1) {
            for (unsigned int i = tid; i < CAND_MAX; i += 1024) {
                unsigned int ixj = i ^ j;
                if (ixj > i) {
                    unsigned long long a = cand[i], b = cand[ixj];
                    bool desc = ((i & k) == 0);
                    if (desc ? (a < b) : (a > b)) { cand[i] = b; cand[ixj] = a; }
                }
            }
            __syncthreads();
        }
    }
    if (tid < DETS) {
        unsigned long long kk = cand[tid];
        unsigned int flat = ~(unsigned int)(kk & 0xFFFFFFFFull);
        float s = sel_score[flat];
        float4 b = ((const float4*)sel_box)[flat];
        out[tid * 4 + 0] = b.x;
        out[tid * 4 + 1] = b.y;
        out[tid * 4 + 2] = b.z;
        out[tid * 4 + 3] = b.w;
        out[400 + tid] = s;
        out[500 + tid] = (float)(flat / TOPK + 1);   // label
    }
}

// ---------------------------------------------------------------------------
extern "C" void kernel_launch(void* const* d_in, const int* in_sizes, int n_in,
                              void* d_out, int out_size, void* d_ws, size_t ws_size,
                              hipStream_t stream) {
    const float* logits    = (const float*)d_in[0];   // [100000, 91]
    const float* box_reg   = (const float*)d_in[1];   // [100000, 364]
    const float* proposals = (const float*)d_in[2];   // [100000, 4]
    float* out = (float*)d_out;                       // 600 floats

    char* ws = (char*)d_ws;
    size_t off = 0;
    auto walloc = [&](size_t bytes) -> char* {
        char* p = ws + off;
        off += (bytes + 255) & ~(size_t)255;
        return p;
    };
    float* scores_t = (float*)walloc((size_t)NFG * N_PROP * sizeof(float)); // 36 MB
    float* sel_score = (float*)walloc((size_t)NFG * TOPK * sizeof(float));
    int*   sel_idx   = (int*)walloc((size_t)NFG * TOPK * sizeof(int));
    float* sel_box   = (float*)walloc((size_t)NFG * TOPK * 4 * sizeof(float));
    unsigned long long* mask =
        (unsigned long long*)walloc((size_t)NFG * TOPK * NWORD * 8); // 11.5 MB
    // selection scratch UNIONED with mask region (last read by sortout_kernel,
    // which runs strictly before mask_kernel's first write)
    unsigned int* ghist1 = (unsigned int*)mask;                 // 90*1024
    unsigned int* ghist2 = ghist1 + NFG * 1024;                 // 90*1024
    unsigned int* gcnt   = ghist2 + NFG * 1024;                 // 90
    unsigned long long* gcand =
        (unsigned long long*)(((uintptr_t)(gcnt + NFG) + 255) & ~(uintptr_t)255);
    (void)ws_size; (void)in_sizes; (void)n_in; (void)out_size;

    const int nzero = NFG * 1024 * 2 + NFG;
    zero_kernel<<<64, 256, 0, stream>>>(ghist1, nzero);
    softmax_kernel<<<(N_PROP + 255) / 256, 256, 0, stream>>>(logits, scores_t);
    hist1_kernel<<<dim3(NFG, 8), 256, 0, stream>>>(scores_t, ghist1);
    hist2_kernel<<<dim3(NFG, 8), 256, 0, stream>>>(scores_t, ghist1, ghist2);
    compact_kernel<<<dim3(NFG, 8), 256, 0, stream>>>(scores_t, ghist1, ghist2,
                                                     gcnt, gcand);
    sortout_kernel<<<NFG, 1024, 0, stream>>>(gcand, gcnt, sel_score, sel_idx);
    decode_kernel<<<(NFG * TOPK + 255) / 256, 256, 0, stream>>>(
        box_reg, proposals, sel_idx, sel_box);
    mask_kernel<<<dim3(NFG, 4, 4), 256, 0, stream>>>(sel_box, mask);
    nms_reduce_kernel<<<NFG, 64, 0, stream>>>(mask, sel_score);
    final_topk_kernel<<<1, 1024, 0, stream>>>(sel_score, sel_box, out);
}

// Round 4
// 582.397 us; speedup vs baseline: 1.4012x; 1.4012x over previous
//
#include <hip/hip_runtime.h>
#include <stdint.h>

#define N_PROP 100000
#define N_CLS  91
#define NFG    90          // foreground classes
#define TOPK   1000
#define NWORD  16          // 1000 bits -> 16 u64 words
#define CAND_MAX 2048
#define DETS   100
#define CHUNKS 16
#define CHUNK  6250        // N_PROP / CHUNKS
#define SCORE_THRESH 0.05f
#define BBOX_CLIP 4.135166556742356f   // log(1000/16)

__device__ __forceinline__ float clampf(float v, float lo, float hi) {
    return fminf(fmaxf(v, lo), hi);
}

// ---------------------------------------------------------------------------
// Kernel 0: zero the global histogram / counter scratch
// ---------------------------------------------------------------------------
__global__ __launch_bounds__(256) void zero_kernel(
    unsigned int* __restrict__ p, int n) {
    for (int i = blockIdx.x * 256 + threadIdx.x; i < n; i += gridDim.x * 256)
        p[i] = 0u;
}

// ---------------------------------------------------------------------------
// Kernel 1: softmax over 91 classes, write transposed scores_t[90][N_PROP]
// ---------------------------------------------------------------------------
__global__ __launch_bounds__(256) void softmax_kernel(
    const float* __restrict__ logits, float* __restrict__ scores_t) {
    int row = blockIdx.x * blockDim.x + threadIdx.x;
    if (row >= N_PROP) return;
    const float* lrow = logits + (size_t)row * N_CLS;
    float m = -INFINITY;
    for (int c = 0; c < N_CLS; ++c) m = fmaxf(m, lrow[c]);
    float sum = 0.f;
    for (int c = 0; c < N_CLS; ++c) sum += expf(lrow[c] - m);
    for (int c = 1; c < N_CLS; ++c) {
        float s = expf(lrow[c] - m) / sum;
        scores_t[(size_t)(c - 1) * N_PROP + row] = s;  // coalesced per-c
    }
}

// ---------------------------------------------------------------------------
// Selection (R3: compact's 91k per-element RETURNING global atomics -- 232 us
// of idle-wave latency, VALUBusy 1.3% -- replaced by LDS staging + ONE global
// range-reservation atomic per block; 8 -> 16 chunks for occupancy):
//   hist1: per-class level-1 histogram (bits>>20) into ghist1[c][1024]
//   hist2: per-class level-2 histogram of bin b1 (bits>>10 & 1023)
//   compact: elements with (bits>>10) >= thresh22 -> gcand[c] (block-agg)
//   sortout: bitonic sort (1024 fast path) -> sel_score/sel_idx
// Candidate order in gcand is irrelevant: sortout totally orders by
// (score_bits desc, idx asc), bit-identical to the reference top_k.
// ---------------------------------------------------------------------------
__device__ __forceinline__ void suffix_scan_1024(unsigned int* sh, int tid) {
    for (int off = 1; off < 1024; off <<= 1) {
        unsigned int v[4];
#pragma unroll
        for (int q = 0; q < 4; ++q) {
            int x = tid + q * 256;
            v[q] = (x + off < 1024) ? sh[x + off] : 0u;
        }
        __syncthreads();
#pragma unroll
        for (int q = 0; q < 4; ++q) sh[tid + q * 256] += v[q];
        __syncthreads();
    }
}

__global__ __launch_bounds__(256) void hist1_kernel(
    const float* __restrict__ scores_t, unsigned int* __restrict__ ghist1) {
    const int c = blockIdx.x, chunk = blockIdx.y, tid = threadIdx.x;
    __shared__ unsigned int lh[4][1024];
    for (int i = tid; i < 4096; i += 256) (&lh[0][0])[i] = 0u;
    __syncthreads();
    const float* sc = scores_t + (size_t)c * N_PROP + chunk * CHUNK;
    for (int i = tid; i < CHUNK; i += 256) {
        unsigned int bits = __float_as_uint(sc[i]);
        atomicAdd(&lh[tid & 3][bits >> 20], 1u);
    }
    __syncthreads();
    for (int b = tid; b < 1024; b += 256) {
        unsigned int v = lh[0][b] + lh[1][b] + lh[2][b] + lh[3][b];
        if (v) atomicAdd(&ghist1[c * 1024 + b], v);
    }
}

__global__ __launch_bounds__(256) void hist2_kernel(
    const float* __restrict__ scores_t, const unsigned int* __restrict__ ghist1,
    unsigned int* __restrict__ ghist2) {
    const int c = blockIdx.x, chunk = blockIdx.y, tid = threadIdx.x;
    __shared__ unsigned int sh[1024];
    __shared__ unsigned int s_b1;
#pragma unroll
    for (int q = 0; q < 4; ++q) sh[tid + q * 256] = ghist1[c * 1024 + tid + q * 256];
    __syncthreads();
    suffix_scan_1024(sh, tid);
#pragma unroll
    for (int q = 0; q < 4; ++q) {
        int x = tid + q * 256;
        if (sh[x] >= TOPK && (x == 1023 || sh[x + 1] < TOPK)) s_b1 = (unsigned)x;
    }
    __syncthreads();
    const unsigned int b1 = s_b1;
    __syncthreads();
#pragma unroll
    for (int q = 0; q < 4; ++q) sh[tid + q * 256] = 0u;   // reuse as local hist2
    __syncthreads();
    const float* sc = scores_t + (size_t)c * N_PROP + chunk * CHUNK;
    for (int i = tid; i < CHUNK; i += 256) {
        unsigned int bits = __float_as_uint(sc[i]);
        if ((bits >> 20) == b1) atomicAdd(&sh[(bits >> 10) & 1023u], 1u);
    }
    __syncthreads();
    for (int b = tid; b < 1024; b += 256)
        if (sh[b]) atomicAdd(&ghist2[c * 1024 + b], sh[b]);
}

__global__ __launch_bounds__(256) void compact_kernel(
    const float* __restrict__ scores_t, const unsigned int* __restrict__ ghist1,
    const unsigned int* __restrict__ ghist2, unsigned int* __restrict__ gcnt,
    unsigned long long* __restrict__ gcand) {
    const int c = blockIdx.x, chunk = blockIdx.y, tid = threadIdx.x;
    __shared__ unsigned int sh[1024];
    __shared__ unsigned long long stage[CAND_MAX];
    __shared__ unsigned int s_b1, s_above, s_b2, s_lcnt, s_base;
    if (tid == 0) s_lcnt = 0u;
#pragma unroll
    for (int q = 0; q < 4; ++q) sh[tid + q * 256] = ghist1[c * 1024 + tid + q * 256];
    __syncthreads();
    suffix_scan_1024(sh, tid);
#pragma unroll
    for (int q = 0; q < 4; ++q) {
        int x = tid + q * 256;
        if (sh[x] >= TOPK && (x == 1023 || sh[x + 1] < TOPK)) {
            s_b1 = (unsigned)x;
            s_above = (x == 1023) ? 0u : sh[x + 1];
        }
    }
    __syncthreads();
    const unsigned int b1 = s_b1;
    const unsigned int need2 = TOPK - s_above;
    __syncthreads();
#pragma unroll
    for (int q = 0; q < 4; ++q) sh[tid + q * 256] = ghist2[c * 1024 + tid + q * 256];
    __syncthreads();
    suffix_scan_1024(sh, tid);
#pragma unroll
    for (int q = 0; q < 4; ++q) {
        int x = tid + q * 256;
        if (sh[x] >= need2 && (x == 1023 || sh[x + 1] < need2)) s_b2 = (unsigned)x;
    }
    __syncthreads();
    const unsigned int thresh22 = (b1 << 10) | s_b2;
    const float* sc = scores_t + (size_t)c * N_PROP + chunk * CHUNK;
    const int ibase = chunk * CHUNK;
    // collect survivors into LDS (LDS atomic only; ~60 per block)
    for (int i = tid; i < CHUNK; i += 256) {
        unsigned int bits = __float_as_uint(sc[i]);
        if ((bits >> 10) >= thresh22) {
            unsigned int pos = atomicAdd(&s_lcnt, 1u);
            if (pos < CAND_MAX)
                stage[pos] = ((unsigned long long)bits << 32) |
                             (unsigned int)(~(unsigned int)(ibase + i));
        }
    }
    __syncthreads();
    unsigned int lcnt = s_lcnt < CAND_MAX ? s_lcnt : CAND_MAX;
    if (tid == 0) s_base = atomicAdd(&gcnt[c], lcnt);  // ONE global atomic
    __syncthreads();
    const unsigned int base = s_base;
    for (unsigned int i = tid; i < lcnt; i += 256) {
        unsigned int pos = base + i;
        if (pos < CAND_MAX) gcand[(size_t)c * CAND_MAX + pos] = stage[i];
    }
}

__global__ __launch_bounds__(1024) void sortout_kernel(
    const unsigned long long* __restrict__ gcand,
    const unsigned int* __restrict__ gcnt,
    float* __restrict__ sel_score, int* __restrict__ sel_idx) {
    const int c = blockIdx.x, tid = threadIdx.x;
    __shared__ unsigned long long cand[CAND_MAX];
    unsigned int cnt = gcnt[c];
    if (cnt > CAND_MAX) cnt = CAND_MAX;
    // fast path: per-class candidate count is ~1000-1010 -> sort 1024 keys
    const unsigned int n = (cnt <= 1024u) ? 1024u : (unsigned)CAND_MAX;
    for (unsigned int i = tid; i < n; i += 1024)
        cand[i] = (i < cnt) ? gcand[(size_t)c * CAND_MAX + i] : 0ull;
    __syncthreads();
    for (unsigned int k = 2; k <= n; k <<= 1) {
        for (unsigned int j = k >> 1; j > 0; j >>= 1) {
            for (unsigned int i = tid; i < n; i += 1024) {
                unsigned int ixj = i ^ j;
                if (ixj > i) {
                    unsigned long long a = cand[i], b = cand[ixj];
                    bool desc = ((i & k) == 0);
                    if (desc ? (a < b) : (a > b)) { cand[i] = b; cand[ixj] = a; }
                }
            }
            __syncthreads();
        }
    }
    if (tid < TOPK) {
        unsigned long long kk = cand[tid];
        sel_score[c * TOPK + tid] = __uint_as_float((unsigned int)(kk >> 32));
        sel_idx[c * TOPK + tid] = (int)(~(unsigned int)(kk & 0xFFFFFFFFull));
    }
}

// ---------------------------------------------------------------------------
// Kernel 3: decode + clip the 90k selected boxes only
// ---------------------------------------------------------------------------
__global__ __launch_bounds__(256) void decode_kernel(
    const float* __restrict__ box_reg, const float* __restrict__ proposals,
    const int* __restrict__ sel_idx, float* __restrict__ sel_box) {
#pragma clang fp contract(off)
    int t = blockIdx.x * blockDim.x + threadIdx.x;
    if (t >= NFG * TOPK) return;
    int c = t / TOPK;           // fg class index, label = c+1
    int i = sel_idx[t];
    float x1 = proposals[i * 4 + 0], y1 = proposals[i * 4 + 1];
    float x2 = proposals[i * 4 + 2], y2 = proposals[i * 4 + 3];
    float w = x2 - x1 + 1.0f, h = y2 - y1 + 1.0f;
    float cx = x1 + 0.5f * w, cy = y1 + 0.5f * h;
    const float* d = box_reg + (size_t)i * (N_CLS * 4) + (size_t)(c + 1) * 4;
    float dx = d[0] / 10.0f, dy = d[1] / 10.0f;
    float dw = fminf(d[2] / 5.0f, BBOX_CLIP);
    float dh = fminf(d[3] / 5.0f, BBOX_CLIP);
    float pcx = dx * w + cx, pcy = dy * h + cy;
    float pw = expf(dw) * w, ph = expf(dh) * h;
    float ox1 = clampf(pcx - 0.5f * pw, 0.f, 1332.f);
    float oy1 = clampf(pcy - 0.5f * ph, 0.f, 799.f);
    float ox2 = clampf(pcx + 0.5f * pw - 1.0f, 0.f, 1332.f);
    float oy2 = clampf(pcy + 0.5f * ph - 1.0f, 0.f, 799.f);
    float4 o = make_float4(ox1, oy1, ox2, oy2);
    ((float4*)sel_box)[t] = o;
}

// ---------------------------------------------------------------------------
// Kernel 4a: suppression bitmask. Grid (class, 4 row-chunks, 4 j-tiles).
// Broadcast LDS reads (0 conflicts); area[j] recomputed in VALU.
// ---------------------------------------------------------------------------
__global__ __launch_bounds__(256) void mask_kernel(
    const float* __restrict__ sel_box, unsigned long long* __restrict__ mask) {
#pragma clang fp contract(off)
    const int c = blockIdx.x;
    const int rbase = blockIdx.y * 256;
    const int jbase0 = blockIdx.z * 256;   // tile of 4 words
    const int r = rbase + threadIdx.x;
    unsigned long long* mrow = mask + ((size_t)c * TOPK + r) * NWORD;
    if (jbase0 + 255 <= rbase) {           // whole tile below diagonal
        if (r < TOPK) {
#pragma unroll
            for (int w4 = 0; w4 < 4; ++w4) mrow[blockIdx.z * 4 + w4] = 0ull;
        }
        return;
    }
    __shared__ float4 box[256];
    {
        int jload = jbase0 + threadIdx.x;
        if (jload < TOPK)
            box[threadIdx.x] = ((const float4*)sel_box)[c * TOPK + jload];
    }
    __syncthreads();
    if (r >= TOPK) return;
    const float4 br = ((const float4*)sel_box)[c * TOPK + r];
    const float ar = (br.z - br.x + 1.0f) * (br.w - br.y + 1.0f);
    for (int w4 = 0; w4 < 4; ++w4) {
        const int wglob = blockIdx.z * 4 + w4;
        const int jbase = wglob * 64;
        if (jbase + 63 <= r) { mrow[wglob] = 0ull; continue; }
        unsigned long long bits = 0ull;
        const int jend = (jbase + 64 < TOPK) ? jbase + 64 : TOPK;
        for (int j = jbase; j < jend; ++j) {
            float4 bj = box[j - jbase0];         // broadcast (uniform addr)
            float aj = (bj.z - bj.x + 1.0f) * (bj.w - bj.y + 1.0f);
            float ltx = fmaxf(br.x, bj.x), lty = fmaxf(br.y, bj.y);
            float rbx = fminf(br.z, bj.z), rby = fminf(br.w, bj.w);
            float iw = fmaxf(rbx - ltx + 1.0f, 0.f);
            float ih = fmaxf(rby - lty + 1.0f, 0.f);
            float inter = iw * ih;
            float uni = ar + aj - inter;
            float diff = (inter + inter) - uni;  // sign always exact
            bool sup;
            if (uni > 0.f && fabsf(diff) > uni * 5e-7f) {
                sup = diff > 0.f;                // fast path (taken ~always)
            } else {
                sup = (inter / uni) > 0.5f;      // exact-window fallback
            }
            if (sup && j > r) bits |= 1ull << (j - jbase);
        }
        mrow[wglob] = bits;
    }
}

// ---------------------------------------------------------------------------
// Kernel 4b: serial greedy sweep over the bitmask, one wave per class.
// ---------------------------------------------------------------------------
__global__ __launch_bounds__(64) void nms_reduce_kernel(
    const unsigned long long* __restrict__ mask, float* __restrict__ sel_score) {
    const int c = blockIdx.x;
    const int lane = threadIdx.x;
    __shared__ unsigned long long keep_lds[NWORD];

    unsigned long long keep = 0ull;
    for (int w = 0; w < NWORD; ++w) {
        int j = w * 64 + lane;
        float s = (j < TOPK) ? sel_score[c * TOPK + j] : -1.0f;
        unsigned long long m = __ballot(s > SCORE_THRESH);
        if (lane == w) keep = m;
    }

    const unsigned long long* mrow = mask + (size_t)c * TOPK * NWORD;
    const int w = (lane < NWORD) ? lane : 0;
    unsigned long long pre[8];
#pragma unroll
    for (int d = 0; d < 8; ++d) pre[d] = mrow[(size_t)d * NWORD + w];

    for (int i = 0; i < TOPK; i += 8) {
#pragma unroll
        for (int d = 0; d < 8; ++d) {
            int ii = i + d;
            unsigned long long row = pre[d];
            pre[d] = (ii + 8 < TOPK) ? mrow[(size_t)(ii + 8) * NWORD + w] : 0ull;
            unsigned long long kw = __shfl(keep, ii >> 6);
            if ((kw >> (ii & 63)) & 1ull) keep &= ~row;
        }
    }
    if (lane < NWORD) keep_lds[lane] = keep;
    __syncthreads();
    for (int j = lane; j < TOPK; j += 64) {
        bool k = (keep_lds[j >> 6] >> (j & 63)) & 1ull;
        if (!k) sel_score[c * TOPK + j] = -1.0f;
    }
}

// ---------------------------------------------------------------------------
// Kernel 5: global top-100 of the 90000 candidate scores (stable desc)
// ---------------------------------------------------------------------------
__global__ __launch_bounds__(1024) void final_topk_kernel(
    const float* __restrict__ sel_score, const float* __restrict__ sel_box,
    float* __restrict__ out) {
    const int tid = threadIdx.x;
    const int M = NFG * TOPK;
    __shared__ unsigned int hist[8][1024];
    __shared__ unsigned long long cand[CAND_MAX];
    __shared__ unsigned int s_cnt, s_b1, s_above, s_b2;

    unsigned int local = 0;
    for (int i = tid; i < M; i += 1024) local += (sel_score[i] > SCORE_THRESH);
    hist[0][tid] = local;
    __syncthreads();
    for (int off = 512; off > 0; off >>= 1) {
        if (tid < off) hist[0][tid] += hist[0][tid + off];
        __syncthreads();
    }
    const bool usefilter = hist[0][0] >= DETS;
    __syncthreads();
    for (int i = tid; i < 8 * 1024; i += 1024) (&hist[0][0])[i] = 0u;
    if (tid == 0) s_cnt = 0u;
    __syncthreads();

    for (int i = tid; i < M; i += 1024) {
        float s = sel_score[i];
        if (usefilter && !(s > SCORE_THRESH)) continue;
        unsigned int u = __float_as_uint(s);
        unsigned int o = (u & 0x80000000u) ? ~u : (u | 0x80000000u);
        atomicAdd(&hist[tid & 7][o >> 22], 1u);
    }
    __syncthreads();
    unsigned int merged = 0;
    for (int r = 0; r < 8; ++r) merged += hist[r][tid];
    __syncthreads();
    hist[0][tid] = merged;
    __syncthreads();
    for (int off = 1; off < 1024; off <<= 1) {
        unsigned int v = (tid + off < 1024) ? hist[0][tid + off] : 0u;
        __syncthreads();
        hist[0][tid] += v;
        __syncthreads();
    }
    if (hist[0][tid] >= DETS && (tid == 1023 || hist[0][tid + 1] < DETS)) {
        s_b1 = (unsigned)tid;
        s_above = (tid == 1023) ? 0u : hist[0][tid + 1];
    }
    __syncthreads();
    const unsigned int b1 = s_b1, above = s_above;
    const unsigned int need2 = DETS - above;
    __syncthreads();
    hist[0][tid] = 0u;
    __syncthreads();
    for (int i = tid; i < M; i += 1024) {
        float s = sel_score[i];
        if (usefilter && !(s > SCORE_THRESH)) continue;
        unsigned int u = __float_as_uint(s);
        unsigned int o = (u & 0x80000000u) ? ~u : (u | 0x80000000u);
        if ((o >> 22) == b1) atomicAdd(&hist[0][(o >> 12) & 1023u], 1u);
    }
    __syncthreads();
    for (int off = 1; off < 1024; off <<= 1) {
        unsigned int v = (tid + off < 1024) ? hist[0][tid + off] : 0u;
        __syncthreads();
        hist[0][tid] += v;
        __syncthreads();
    }
    if (hist[0][tid] >= need2 && (tid == 1023 || hist[0][tid + 1] < need2))
        s_b2 = (unsigned)tid;
    __syncthreads();
    const unsigned int thresh20 = (b1 << 10) | s_b2;
    for (int i = tid; i < M; i += 1024) {
        float s = sel_score[i];
        if (usefilter && !(s > SCORE_THRESH)) continue;
        unsigned int u = __float_as_uint(s);
        unsigned int o = (u & 0x80000000u) ? ~u : (u | 0x80000000u);
        if ((o >> 12) >= thresh20) {
            unsigned int pos = atomicAdd(&s_cnt, 1u);
            if (pos < CAND_MAX)
                cand[pos] = ((unsigned long long)o << 32) |
                            (unsigned int)(~(unsigned int)i);
        }
    }
    __syncthreads();
    unsigned int cnt = s_cnt < CAND_MAX ? s_cnt : CAND_MAX;
    for (int i = tid; i < CAND_MAX; i += 1024)
        if ((unsigned)i >= cnt) cand[i] = 0ull;
    __syncthreads();
    for (unsigned int k = 2; k <= CAND_MAX; k <<= 1) {
        for (unsigned int j = k >> 1; j > 0; j >>= 1) {
            for (unsigned int i = tid; i < CAND_MAX; i += 1024) {
                unsigned int ixj = i ^ j;
                if (ixj > i) {
                    unsigned long long a = cand[i], b = cand[ixj];
                    bool desc = ((i & k) == 0);
                    if (desc ? (a < b) : (a > b)) { cand[i] = b; cand[ixj] = a; }
                }
            }
            __syncthreads();
        }
    }
    if (tid < DETS) {
        unsigned long long kk = cand[tid];
        unsigned int flat = ~(unsigned int)(kk & 0xFFFFFFFFull);
        float s = sel_score[flat];
        float4 b = ((const float4*)sel_box)[flat];
        out[tid * 4 + 0] = b.x;
        out[tid * 4 + 1] = b.y;
        out[tid * 4 + 2] = b.z;
        out[tid * 4 + 3] = b.w;
        out[400 + tid] = s;
        out[500 + tid] = (float)(flat / TOPK + 1);   // label
    }
}

// ---------------------------------------------------------------------------
extern "C" void kernel_launch(void* const* d_in, const int* in_sizes, int n_in,
                              void* d_out, int out_size, void* d_ws, size_t ws_size,
                              hipStream_t stream) {
    const float* logits    = (const float*)d_in[0];   // [100000, 91]
    const float* box_reg   = (const float*)d_in[1];   // [100000, 364]
    const float* proposals = (const float*)d_in[2];   // [100000, 4]
    float* out = (float*)d_out;                       // 600 floats

    char* ws = (char*)d_ws;
    size_t off = 0;
    auto walloc = [&](size_t bytes) -> char* {
        char* p = ws + off;
        off += (bytes + 255) & ~(size_t)255;
        return p;
    };
    float* scores_t = (float*)walloc((size_t)NFG * N_PROP * sizeof(float)); // 36 MB
    float* sel_score = (float*)walloc((size_t)NFG * TOPK * sizeof(float));
    int*   sel_idx   = (int*)walloc((size_t)NFG * TOPK * sizeof(int));
    float* sel_box   = (float*)walloc((size_t)NFG * TOPK * 4 * sizeof(float));
    unsigned long long* mask =
        (unsigned long long*)walloc((size_t)NFG * TOPK * NWORD * 8); // 11.5 MB
    // selection scratch UNIONED with mask region (last read by sortout_kernel,
    // which runs strictly before mask_kernel's first write)
    unsigned int* ghist1 = (unsigned int*)mask;                 // 90*1024
    unsigned int* ghist2 = ghist1 + NFG * 1024;                 // 90*1024
    unsigned int* gcnt   = ghist2 + NFG * 1024;                 // 90
    unsigned long long* gcand =
        (unsigned long long*)(((uintptr_t)(gcnt + NFG) + 255) & ~(uintptr_t)255);
    (void)ws_size; (void)in_sizes; (void)n_in; (void)out_size;

    const int nzero = NFG * 1024 * 2 + NFG;
    zero_kernel<<<64, 256, 0, stream>>>(ghist1, nzero);
    softmax_kernel<<<(N_PROP + 255) / 256, 256, 0, stream>>>(logits, scores_t);
    hist1_kernel<<<dim3(NFG, CHUNKS), 256, 0, stream>>>(scores_t, ghist1);
    hist2_kernel<<<dim3(NFG, CHUNKS), 256, 0, stream>>>(scores_t, ghist1, ghist2);
    compact_kernel<<<dim3(NFG, CHUNKS), 256, 0, stream>>>(scores_t, ghist1, ghist2,
                                                          gcnt, gcand);
    sortout_kernel<<<NFG, 1024, 0, stream>>>(gcand, gcnt, sel_score, sel_idx);
    decode_kernel<<<(NFG * TOPK + 255) / 256, 256, 0, stream>>>(
        box_reg, proposals, sel_idx, sel_box);
    mask_kernel<<<dim3(NFG, 4, 4), 256, 0, stream>>>(sel_box, mask);
    nms_reduce_kernel<<<NFG, 64, 0, stream>>>(mask, sel_score);
    final_topk_kernel<<<1, 1024, 0, stream>>>(sel_score, sel_box, out);
}

// Round 5
// 509.828 us; speedup vs baseline: 1.6006x; 1.1423x over previous
//
#include <hip/hip_runtime.h>
#include <stdint.h>

#define N_PROP 100000
#define N_CLS  91
#define NFG    90          // foreground classes
#define TOPK   1000
#define NWORD  16          // 1000 bits -> 16 u64 words
#define CAND_MAX 2048
#define DETS   100
#define CHUNKS 16
#define CHUNK  6250        // N_PROP / CHUNKS
#define SCORE_THRESH 0.05f
#define BBOX_CLIP 4.135166556742356f   // log(1000/16)

__device__ __forceinline__ float clampf(float v, float lo, float hi) {
    return fminf(fmaxf(v, lo), hi);
}

// ---------------------------------------------------------------------------
// Kernel 0: zero two scratch regions
// ---------------------------------------------------------------------------
__global__ __launch_bounds__(256) void zero_kernel(
    unsigned int* __restrict__ p1, int n1,
    unsigned int* __restrict__ p2, int n2) {
    for (int i = blockIdx.x * 256 + threadIdx.x; i < n1; i += gridDim.x * 256)
        p1[i] = 0u;
    for (int i = blockIdx.x * 256 + threadIdx.x; i < n2; i += gridDim.x * 256)
        p2[i] = 0u;
}

// ---------------------------------------------------------------------------
// Kernel 1: softmax over 91 classes, write transposed scores_t[90][N_PROP]
// ---------------------------------------------------------------------------
__global__ __launch_bounds__(256) void softmax_kernel(
    const float* __restrict__ logits, float* __restrict__ scores_t) {
    int row = blockIdx.x * blockDim.x + threadIdx.x;
    if (row >= N_PROP) return;
    const float* lrow = logits + (size_t)row * N_CLS;
    float m = -INFINITY;
    for (int c = 0; c < N_CLS; ++c) m = fmaxf(m, lrow[c]);
    float sum = 0.f;
    for (int c = 0; c < N_CLS; ++c) sum += expf(lrow[c] - m);
    for (int c = 1; c < N_CLS; ++c) {
        float s = expf(lrow[c] - m) / sum;
        scores_t[(size_t)(c - 1) * N_PROP + row] = s;  // coalesced per-c
    }
}

// ---------------------------------------------------------------------------
// Per-class selection (hist1/hist2/compact/sortout) — unchanged from R3.
// ---------------------------------------------------------------------------
__device__ __forceinline__ void suffix_scan_1024(unsigned int* sh, int tid) {
    for (int off = 1; off < 1024; off <<= 1) {
        unsigned int v[4];
#pragma unroll
        for (int q = 0; q < 4; ++q) {
            int x = tid + q * 256;
            v[q] = (x + off < 1024) ? sh[x + off] : 0u;
        }
        __syncthreads();
#pragma unroll
        for (int q = 0; q < 4; ++q) sh[tid + q * 256] += v[q];
        __syncthreads();
    }
}

__global__ __launch_bounds__(256) void hist1_kernel(
    const float* __restrict__ scores_t, unsigned int* __restrict__ ghist1) {
    const int c = blockIdx.x, chunk = blockIdx.y, tid = threadIdx.x;
    __shared__ unsigned int lh[4][1024];
    for (int i = tid; i < 4096; i += 256) (&lh[0][0])[i] = 0u;
    __syncthreads();
    const float* sc = scores_t + (size_t)c * N_PROP + chunk * CHUNK;
    for (int i = tid; i < CHUNK; i += 256) {
        unsigned int bits = __float_as_uint(sc[i]);
        atomicAdd(&lh[tid & 3][bits >> 20], 1u);
    }
    __syncthreads();
    for (int b = tid; b < 1024; b += 256) {
        unsigned int v = lh[0][b] + lh[1][b] + lh[2][b] + lh[3][b];
        if (v) atomicAdd(&ghist1[c * 1024 + b], v);
    }
}

__global__ __launch_bounds__(256) void hist2_kernel(
    const float* __restrict__ scores_t, const unsigned int* __restrict__ ghist1,
    unsigned int* __restrict__ ghist2) {
    const int c = blockIdx.x, chunk = blockIdx.y, tid = threadIdx.x;
    __shared__ unsigned int sh[1024];
    __shared__ unsigned int s_b1;
#pragma unroll
    for (int q = 0; q < 4; ++q) sh[tid + q * 256] = ghist1[c * 1024 + tid + q * 256];
    __syncthreads();
    suffix_scan_1024(sh, tid);
#pragma unroll
    for (int q = 0; q < 4; ++q) {
        int x = tid + q * 256;
        if (sh[x] >= TOPK && (x == 1023 || sh[x + 1] < TOPK)) s_b1 = (unsigned)x;
    }
    __syncthreads();
    const unsigned int b1 = s_b1;
    __syncthreads();
#pragma unroll
    for (int q = 0; q < 4; ++q) sh[tid + q * 256] = 0u;   // reuse as local hist2
    __syncthreads();
    const float* sc = scores_t + (size_t)c * N_PROP + chunk * CHUNK;
    for (int i = tid; i < CHUNK; i += 256) {
        unsigned int bits = __float_as_uint(sc[i]);
        if ((bits >> 20) == b1) atomicAdd(&sh[(bits >> 10) & 1023u], 1u);
    }
    __syncthreads();
    for (int b = tid; b < 1024; b += 256)
        if (sh[b]) atomicAdd(&ghist2[c * 1024 + b], sh[b]);
}

__global__ __launch_bounds__(256) void compact_kernel(
    const float* __restrict__ scores_t, const unsigned int* __restrict__ ghist1,
    const unsigned int* __restrict__ ghist2, unsigned int* __restrict__ gcnt,
    unsigned long long* __restrict__ gcand) {
    const int c = blockIdx.x, chunk = blockIdx.y, tid = threadIdx.x;
    __shared__ unsigned int sh[1024];
    __shared__ unsigned long long stage[CAND_MAX];
    __shared__ unsigned int s_b1, s_above, s_b2, s_lcnt, s_base;
    if (tid == 0) s_lcnt = 0u;
#pragma unroll
    for (int q = 0; q < 4; ++q) sh[tid + q * 256] = ghist1[c * 1024 + tid + q * 256];
    __syncthreads();
    suffix_scan_1024(sh, tid);
#pragma unroll
    for (int q = 0; q < 4; ++q) {
        int x = tid + q * 256;
        if (sh[x] >= TOPK && (x == 1023 || sh[x + 1] < TOPK)) {
            s_b1 = (unsigned)x;
            s_above = (x == 1023) ? 0u : sh[x + 1];
        }
    }
    __syncthreads();
    const unsigned int b1 = s_b1;
    const unsigned int need2 = TOPK - s_above;
    __syncthreads();
#pragma unroll
    for (int q = 0; q < 4; ++q) sh[tid + q * 256] = ghist2[c * 1024 + tid + q * 256];
    __syncthreads();
    suffix_scan_1024(sh, tid);
#pragma unroll
    for (int q = 0; q < 4; ++q) {
        int x = tid + q * 256;
        if (sh[x] >= need2 && (x == 1023 || sh[x + 1] < need2)) s_b2 = (unsigned)x;
    }
    __syncthreads();
    const unsigned int thresh22 = (b1 << 10) | s_b2;
    const float* sc = scores_t + (size_t)c * N_PROP + chunk * CHUNK;
    const int ibase = chunk * CHUNK;
    for (int i = tid; i < CHUNK; i += 256) {
        unsigned int bits = __float_as_uint(sc[i]);
        if ((bits >> 10) >= thresh22) {
            unsigned int pos = atomicAdd(&s_lcnt, 1u);
            if (pos < CAND_MAX)
                stage[pos] = ((unsigned long long)bits << 32) |
                             (unsigned int)(~(unsigned int)(ibase + i));
        }
    }
    __syncthreads();
    unsigned int lcnt = s_lcnt < CAND_MAX ? s_lcnt : CAND_MAX;
    if (tid == 0) s_base = atomicAdd(&gcnt[c], lcnt);  // ONE global atomic
    __syncthreads();
    const unsigned int base = s_base;
    for (unsigned int i = tid; i < lcnt; i += 256) {
        unsigned int pos = base + i;
        if (pos < CAND_MAX) gcand[(size_t)c * CAND_MAX + pos] = stage[i];
    }
}

__global__ __launch_bounds__(1024) void sortout_kernel(
    const unsigned long long* __restrict__ gcand,
    const unsigned int* __restrict__ gcnt,
    float* __restrict__ sel_score, int* __restrict__ sel_idx) {
    const int c = blockIdx.x, tid = threadIdx.x;
    __shared__ unsigned long long cand[CAND_MAX];
    unsigned int cnt = gcnt[c];
    if (cnt > CAND_MAX) cnt = CAND_MAX;
    const unsigned int n = (cnt <= 1024u) ? 1024u : (unsigned)CAND_MAX;
    for (unsigned int i = tid; i < n; i += 1024)
        cand[i] = (i < cnt) ? gcand[(size_t)c * CAND_MAX + i] : 0ull;
    __syncthreads();
    for (unsigned int k = 2; k <= n; k <<= 1) {
        for (unsigned int j = k >> 1; j > 0; j >>= 1) {
            for (unsigned int i = tid; i < n; i += 1024) {
                unsigned int ixj = i ^ j;
                if (ixj > i) {
                    unsigned long long a = cand[i], b = cand[ixj];
                    bool desc = ((i & k) == 0);
                    if (desc ? (a < b) : (a > b)) { cand[i] = b; cand[ixj] = a; }
                }
            }
            __syncthreads();
        }
    }
    if (tid < TOPK) {
        unsigned long long kk = cand[tid];
        sel_score[c * TOPK + tid] = __uint_as_float((unsigned int)(kk >> 32));
        sel_idx[c * TOPK + tid] = (int)(~(unsigned int)(kk & 0xFFFFFFFFull));
    }
}

// ---------------------------------------------------------------------------
// Kernel 3: decode + clip the 90k selected boxes only
// ---------------------------------------------------------------------------
__global__ __launch_bounds__(256) void decode_kernel(
    const float* __restrict__ box_reg, const float* __restrict__ proposals,
    const int* __restrict__ sel_idx, float* __restrict__ sel_box) {
#pragma clang fp contract(off)
    int t = blockIdx.x * blockDim.x + threadIdx.x;
    if (t >= NFG * TOPK) return;
    int c = t / TOPK;           // fg class index, label = c+1
    int i = sel_idx[t];
    float x1 = proposals[i * 4 + 0], y1 = proposals[i * 4 + 1];
    float x2 = proposals[i * 4 + 2], y2 = proposals[i * 4 + 3];
    float w = x2 - x1 + 1.0f, h = y2 - y1 + 1.0f;
    float cx = x1 + 0.5f * w, cy = y1 + 0.5f * h;
    const float* d = box_reg + (size_t)i * (N_CLS * 4) + (size_t)(c + 1) * 4;
    float dx = d[0] / 10.0f, dy = d[1] / 10.0f;
    float dw = fminf(d[2] / 5.0f, BBOX_CLIP);
    float dh = fminf(d[3] / 5.0f, BBOX_CLIP);
    float pcx = dx * w + cx, pcy = dy * h + cy;
    float pw = expf(dw) * w, ph = expf(dh) * h;
    float ox1 = clampf(pcx - 0.5f * pw, 0.f, 1332.f);
    float oy1 = clampf(pcy - 0.5f * ph, 0.f, 799.f);
    float ox2 = clampf(pcx + 0.5f * pw - 1.0f, 0.f, 1332.f);
    float oy2 = clampf(pcy + 0.5f * ph - 1.0f, 0.f, 799.f);
    float4 o = make_float4(ox1, oy1, ox2, oy2);
    ((float4*)sel_box)[t] = o;
}

// ---------------------------------------------------------------------------
// Kernel 4a: suppression bitmask. Grid (class, 4 row-chunks, 4 j-tiles).
// ---------------------------------------------------------------------------
__global__ __launch_bounds__(256) void mask_kernel(
    const float* __restrict__ sel_box, unsigned long long* __restrict__ mask) {
#pragma clang fp contract(off)
    const int c = blockIdx.x;
    const int rbase = blockIdx.y * 256;
    const int jbase0 = blockIdx.z * 256;   // tile of 4 words
    const int r = rbase + threadIdx.x;
    unsigned long long* mrow = mask + ((size_t)c * TOPK + r) * NWORD;
    if (jbase0 + 255 <= rbase) {           // whole tile below diagonal
        if (r < TOPK) {
#pragma unroll
            for (int w4 = 0; w4 < 4; ++w4) mrow[blockIdx.z * 4 + w4] = 0ull;
        }
        return;
    }
    __shared__ float4 box[256];
    {
        int jload = jbase0 + threadIdx.x;
        if (jload < TOPK)
            box[threadIdx.x] = ((const float4*)sel_box)[c * TOPK + jload];
    }
    __syncthreads();
    if (r >= TOPK) return;
    const float4 br = ((const float4*)sel_box)[c * TOPK + r];
    const float ar = (br.z - br.x + 1.0f) * (br.w - br.y + 1.0f);
    for (int w4 = 0; w4 < 4; ++w4) {
        const int wglob = blockIdx.z * 4 + w4;
        const int jbase = wglob * 64;
        if (jbase + 63 <= r) { mrow[wglob] = 0ull; continue; }
        unsigned long long bits = 0ull;
        const int jend = (jbase + 64 < TOPK) ? jbase + 64 : TOPK;
        for (int j = jbase; j < jend; ++j) {
            float4 bj = box[j - jbase0];         // broadcast (uniform addr)
            float aj = (bj.z - bj.x + 1.0f) * (bj.w - bj.y + 1.0f);
            float ltx = fmaxf(br.x, bj.x), lty = fmaxf(br.y, bj.y);
            float rbx = fminf(br.z, bj.z), rby = fminf(br.w, bj.w);
            float iw = fmaxf(rbx - ltx + 1.0f, 0.f);
            float ih = fmaxf(rby - lty + 1.0f, 0.f);
            float inter = iw * ih;
            float uni = ar + aj - inter;
            float diff = (inter + inter) - uni;  // sign always exact
            bool sup;
            if (uni > 0.f && fabsf(diff) > uni * 5e-7f) {
                sup = diff > 0.f;                // fast path (taken ~always)
            } else {
                sup = (inter / uni) > 0.5f;      // exact-window fallback
            }
            if (sup && j > r) bits |= 1ull << (j - jbase);
        }
        mrow[wglob] = bits;
    }
}

// ---------------------------------------------------------------------------
// Kernel 4b: serial greedy sweep, one wave per class. R4: fused with the
// final-topk positives count (fpos) and level-1 histogram (fhist1) of the
// KEPT scores -- the data is already in registers here, so the global
// final_topk kernel no longer needs its 3 latency-bound full passes.
// ---------------------------------------------------------------------------
__global__ __launch_bounds__(64) void nms_reduce_kernel(
    const unsigned long long* __restrict__ mask, float* __restrict__ sel_score,
    unsigned int* __restrict__ fpos, unsigned int* __restrict__ fhist1) {
    const int c = blockIdx.x;
    const int lane = threadIdx.x;
    __shared__ unsigned long long keep_lds[NWORD];
    __shared__ unsigned int lh[1024];

    float sval[NWORD];
    unsigned long long keep = 0ull;
    for (int w = 0; w < NWORD; ++w) {
        int j = w * 64 + lane;
        float s = (j < TOPK) ? sel_score[c * TOPK + j] : -1.0f;
        sval[w] = s;
        unsigned long long m = __ballot(s > SCORE_THRESH);
        if (lane == w) keep = m;
    }

    const unsigned long long* mrow = mask + (size_t)c * TOPK * NWORD;
    const int w = (lane < NWORD) ? lane : 0;
    unsigned long long pre[8];
#pragma unroll
    for (int d = 0; d < 8; ++d) pre[d] = mrow[(size_t)d * NWORD + w];

    for (int i = 0; i < TOPK; i += 8) {
#pragma unroll
        for (int d = 0; d < 8; ++d) {
            int ii = i + d;
            unsigned long long row = pre[d];
            pre[d] = (ii + 8 < TOPK) ? mrow[(size_t)(ii + 8) * NWORD + w] : 0ull;
            unsigned long long kw = __shfl(keep, ii >> 6);
            if ((kw >> (ii & 63)) & 1ull) keep &= ~row;
        }
    }
    if (lane < NWORD) keep_lds[lane] = keep;
    for (int b = lane; b < 1024; b += 64) lh[b] = 0u;
    __syncthreads();

    // histogram kept scores (all > SCORE_THRESH > 0 => orderable key = u|sign)
    int mykept = 0;
    for (int ww = 0; ww < NWORD; ++ww) {
        if ((keep_lds[ww] >> lane) & 1ull) {
            unsigned int o = __float_as_uint(sval[ww]) | 0x80000000u;
            atomicAdd(&lh[o >> 22], 1u);
            ++mykept;
        }
    }
#pragma unroll
    for (int off = 32; off > 0; off >>= 1) mykept += __shfl_down(mykept, off);
    if (lane == 0 && mykept) atomicAdd(fpos, (unsigned int)mykept);
    __syncthreads();
    for (int b = lane; b < 1024; b += 64)
        if (lh[b]) atomicAdd(&fhist1[b], lh[b]);

    for (int j = lane; j < TOPK; j += 64) {
        bool k = (keep_lds[j >> 6] >> (j & 63)) & 1ull;
        if (!k) sel_score[c * TOPK + j] = -1.0f;
    }
}

// ---------------------------------------------------------------------------
// Final top-100, parallelized (R4; was one block @106us, occupancy 0.17%).
// Post-NMS values are exactly {score>0.05} U {-1.0}.
//   P >= DETS: two-level histogram select over positives (bit-identical to
//              the reference: -1 entries can never reach the top-100).
//   P <  DETS: compact all positives + first P+DETS flat indices (provably
//              contains the DETS smallest-index -1 entries); sort does the rest.
// ---------------------------------------------------------------------------
__global__ __launch_bounds__(256) void ftk_hist2_kernel(
    const float* __restrict__ sel_score, const unsigned int* __restrict__ fpos,
    const unsigned int* __restrict__ fhist1, unsigned int* __restrict__ fhist2) {
    const int tid = threadIdx.x;
    if (*fpos < DETS) return;
    __shared__ unsigned int sh[1024];
    __shared__ unsigned int s_b1;
#pragma unroll
    for (int q = 0; q < 4; ++q) sh[tid + q * 256] = fhist1[tid + q * 256];
    __syncthreads();
    suffix_scan_1024(sh, tid);
#pragma unroll
    for (int q = 0; q < 4; ++q) {
        int x = tid + q * 256;
        if (sh[x] >= DETS && (x == 1023 || sh[x + 1] < DETS)) s_b1 = (unsigned)x;
    }
    __syncthreads();
    const unsigned int b1 = s_b1;
    __syncthreads();
#pragma unroll
    for (int q = 0; q < 4; ++q) sh[tid + q * 256] = 0u;
    __syncthreads();
    const float* base = sel_score + blockIdx.x * TOPK;
    for (int i = tid; i < TOPK; i += 256) {
        float s = base[i];
        if (!(s > SCORE_THRESH)) continue;
        unsigned int o = __float_as_uint(s) | 0x80000000u;
        if ((o >> 22) == b1) atomicAdd(&sh[(o >> 12) & 1023u], 1u);
    }
    __syncthreads();
    for (int b = tid; b < 1024; b += 256)
        if (sh[b]) atomicAdd(&fhist2[b], sh[b]);
}

__global__ __launch_bounds__(256) void ftk_compact_kernel(
    const float* __restrict__ sel_score, const unsigned int* __restrict__ fpos,
    const unsigned int* __restrict__ fhist1, const unsigned int* __restrict__ fhist2,
    unsigned int* __restrict__ fcnt, unsigned long long* __restrict__ fcand) {
    const int tid = threadIdx.x;
    const unsigned int P = *fpos;
    __shared__ unsigned int sh[1024];
    __shared__ unsigned long long stage[1024];
    __shared__ unsigned int s_b1, s_above, s_b2, s_lcnt, s_base;
    if (tid == 0) s_lcnt = 0u;
    const float* base = sel_score + blockIdx.x * TOPK;
    const int fbase = blockIdx.x * TOPK;
    if (P >= DETS) {
#pragma unroll
        for (int q = 0; q < 4; ++q) sh[tid + q * 256] = fhist1[tid + q * 256];
        __syncthreads();
        suffix_scan_1024(sh, tid);
#pragma unroll
        for (int q = 0; q < 4; ++q) {
            int x = tid + q * 256;
            if (sh[x] >= DETS && (x == 1023 || sh[x + 1] < DETS)) {
                s_b1 = (unsigned)x;
                s_above = (x == 1023) ? 0u : sh[x + 1];
            }
        }
        __syncthreads();
        const unsigned int b1 = s_b1;
        const unsigned int need2 = DETS - s_above;
        __syncthreads();
#pragma unroll
        for (int q = 0; q < 4; ++q) sh[tid + q * 256] = fhist2[tid + q * 256];
        __syncthreads();
        suffix_scan_1024(sh, tid);
#pragma unroll
        for (int q = 0; q < 4; ++q) {
            int x = tid + q * 256;
            if (sh[x] >= need2 && (x == 1023 || sh[x + 1] < need2)) s_b2 = (unsigned)x;
        }
        __syncthreads();
        const unsigned int thresh20 = (s_b1 << 10) | s_b2;
        (void)b1;
        for (int i = tid; i < TOPK; i += 256) {
            float s = base[i];
            if (!(s > SCORE_THRESH)) continue;
            unsigned int o = __float_as_uint(s) | 0x80000000u;
            if ((o >> 12) >= thresh20) {
                unsigned int pos = atomicAdd(&s_lcnt, 1u);
                stage[pos] = ((unsigned long long)o << 32) |
                             (unsigned int)(~(unsigned int)(fbase + i));
            }
        }
    } else {
        for (int i = tid; i < TOPK; i += 256) {
            float s = base[i];
            int flat = fbase + i;
            if ((s > SCORE_THRESH) || flat < (int)(P + DETS)) {
                unsigned int u = __float_as_uint(s);
                unsigned int o = (u & 0x80000000u) ? ~u : (u | 0x80000000u);
                unsigned int pos = atomicAdd(&s_lcnt, 1u);
                stage[pos] = ((unsigned long long)o << 32) |
                             (unsigned int)(~(unsigned int)flat);
            }
        }
    }
    __syncthreads();
    unsigned int lcnt = s_lcnt < 1024u ? s_lcnt : 1024u;
    if (tid == 0) s_base = atomicAdd(fcnt, lcnt);  // ONE global atomic
    __syncthreads();
    const unsigned int bse = s_base;
    for (unsigned int i = tid; i < lcnt; i += 256) {
        unsigned int pos = bse + i;
        if (pos < CAND_MAX) fcand[pos] = stage[i];
    }
}

__global__ __launch_bounds__(1024) void ftk_sort_kernel(
    const unsigned long long* __restrict__ fcand,
    const unsigned int* __restrict__ fcnt,
    const float* __restrict__ sel_score, const float* __restrict__ sel_box,
    float* __restrict__ out) {
    const int tid = threadIdx.x;
    __shared__ unsigned long long cand[CAND_MAX];
    unsigned int cnt = *fcnt;
    if (cnt > CAND_MAX) cnt = CAND_MAX;
    const unsigned int n = (cnt <= 1024u) ? 1024u : (unsigned)CAND_MAX;
    for (unsigned int i = tid; i < n; i += 1024)
        cand[i] = (i < cnt) ? fcand[i] : 0ull;
    __syncthreads();
    for (unsigned int k = 2; k <= n; k <<= 1) {
        for (unsigned int j = k >> 1; j > 0; j >>= 1) {
            for (unsigned int i = tid; i < n; i += 1024) {
                unsigned int ixj = i ^ j;
                if (ixj > i) {
                    unsigned long long a = cand[i], b = cand[ixj];
                    bool desc = ((i & k) == 0);
                    if (desc ? (a < b) : (a > b)) { cand[i] = b; cand[ixj] = a; }
                }
            }
            __syncthreads();
        }
    }
    if (tid < DETS) {
        unsigned long long kk = cand[tid];
        unsigned int flat = ~(unsigned int)(kk & 0xFFFFFFFFull);
        float s = sel_score[flat];
        float4 b = ((const float4*)sel_box)[flat];
        out[tid * 4 + 0] = b.x;
        out[tid * 4 + 1] = b.y;
        out[tid * 4 + 2] = b.z;
        out[tid * 4 + 3] = b.w;
        out[400 + tid] = s;
        out[500 + tid] = (float)(flat / TOPK + 1);   // label
    }
}

// ---------------------------------------------------------------------------
extern "C" void kernel_launch(void* const* d_in, const int* in_sizes, int n_in,
                              void* d_out, int out_size, void* d_ws, size_t ws_size,
                              hipStream_t stream) {
    const float* logits    = (const float*)d_in[0];   // [100000, 91]
    const float* box_reg   = (const float*)d_in[1];   // [100000, 364]
    const float* proposals = (const float*)d_in[2];   // [100000, 4]
    float* out = (float*)d_out;                       // 600 floats

    char* ws = (char*)d_ws;
    size_t off = 0;
    auto walloc = [&](size_t bytes) -> char* {
        char* p = ws + off;
        off += (bytes + 255) & ~(size_t)255;
        return p;
    };
    float* scores_t = (float*)walloc((size_t)NFG * N_PROP * sizeof(float)); // 36 MB
    float* sel_score = (float*)walloc((size_t)NFG * TOPK * sizeof(float));
    int*   sel_idx   = (int*)walloc((size_t)NFG * TOPK * sizeof(int));
    float* sel_box   = (float*)walloc((size_t)NFG * TOPK * 4 * sizeof(float));
    // final-topk scratch (must survive mask writes -> own region)
    unsigned int* fscr = (unsigned int*)walloc((2 + 2048) * sizeof(unsigned int));
    unsigned int* fpos   = fscr;          // [1]
    unsigned int* fcnt   = fscr + 1;      // [1]
    unsigned int* fhist1 = fscr + 2;      // [1024]
    unsigned int* fhist2 = fscr + 2 + 1024; // [1024]
    unsigned long long* fcand =
        (unsigned long long*)walloc(CAND_MAX * sizeof(unsigned long long));
    unsigned long long* mask =
        (unsigned long long*)walloc((size_t)NFG * TOPK * NWORD * 8); // 11.5 MB
    // selection scratch UNIONED with mask region (last read by sortout_kernel,
    // which runs strictly before mask_kernel's first write)
    unsigned int* ghist1 = (unsigned int*)mask;                 // 90*1024
    unsigned int* ghist2 = ghist1 + NFG * 1024;                 // 90*1024
    unsigned int* gcnt   = ghist2 + NFG * 1024;                 // 90
    unsigned long long* gcand =
        (unsigned long long*)(((uintptr_t)(gcnt + NFG) + 255) & ~(uintptr_t)255);
    (void)ws_size; (void)in_sizes; (void)n_in; (void)out_size;

    const int nzero = NFG * 1024 * 2 + NFG;
    zero_kernel<<<64, 256, 0, stream>>>(ghist1, nzero, fscr, 2 + 2048);
    softmax_kernel<<<(N_PROP + 255) / 256, 256, 0, stream>>>(logits, scores_t);
    hist1_kernel<<<dim3(NFG, CHUNKS), 256, 0, stream>>>(scores_t, ghist1);
    hist2_kernel<<<dim3(NFG, CHUNKS), 256, 0, stream>>>(scores_t, ghist1, ghist2);
    compact_kernel<<<dim3(NFG, CHUNKS), 256, 0, stream>>>(scores_t, ghist1, ghist2,
                                                          gcnt, gcand);
    sortout_kernel<<<NFG, 1024, 0, stream>>>(gcand, gcnt, sel_score, sel_idx);
    decode_kernel<<<(NFG * TOPK + 255) / 256, 256, 0, stream>>>(
        box_reg, proposals, sel_idx, sel_box);
    mask_kernel<<<dim3(NFG, 4, 4), 256, 0, stream>>>(sel_box, mask);
    nms_reduce_kernel<<<NFG, 64, 0, stream>>>(mask, sel_score, fpos, fhist1);
    ftk_hist2_kernel<<<NFG, 256, 0, stream>>>(sel_score, fpos, fhist1, fhist2);
    ftk_compact_kernel<<<NFG, 256, 0, stream>>>(sel_score, fpos, fhist1, fhist2,
                                                fcnt, fcand);
    ftk_sort_kernel<<<1, 1024, 0, stream>>>(fcand, fcnt, sel_score, sel_box, out);
}